// Round 1
// baseline (150.660 us; speedup 1.0000x reference)
//
#include <hip/hip_runtime.h>
#include <hip/hip_bf16.h>

// Problem shapes
#define B_SZ 64
#define T_PTS 300
#define N_SEG 299
#define VM 34            // 17*2
#define NPATH (B_SZ*VM)  // 2176
#define SIGC 120         // 3+9+27+81
#define FAN1 4080        // 34*120
#define H1 512
#define NOUT 155
#define CHUNK 5          // segments per lane (64*5=320 >= 299)

// ---------------------------------------------------------------------------
// Chen / signature helpers. State: a1[3], a2[9], a3[27], a4[81] (flattened,
// row-major tensor-product ordering matching signatory/reference).
// ---------------------------------------------------------------------------

// Absorb one linear segment with increment (d0,d1,d2):
//   seg levels g1=dx, g2=dx^2/2, g3=dx^3/6, g4=dx^4/24
//   n4 = a4 + a3(x)g1 + a2(x)g2 + a1(x)g3 + g4, etc.
__device__ __forceinline__ void sig_append(float a1[3], float a2[9], float a3[27], float a4[81],
                                           float d0, float d1, float d2) {
  float B1[3] = {d0, d1, d2};
  float Hh[3] = {0.5f * d0, 0.5f * d1, 0.5f * d2};
  float Tt[3] = {(1.0f / 3.0f) * d0, (1.0f / 3.0f) * d1, (1.0f / 3.0f) * d2};
  float Qq[3] = {0.25f * d0, 0.25f * d1, 0.25f * d2};
  float B2[9], B3[27];
#pragma unroll
  for (int i = 0; i < 3; i++)
#pragma unroll
    for (int j = 0; j < 3; j++) B2[i * 3 + j] = B1[i] * Hh[j];
#pragma unroll
  for (int e = 0; e < 27; e++) B3[e] = B2[e / 3] * Tt[e % 3];

#pragma unroll
  for (int e = 0; e < 81; e++) {
    float v = a4[e];
    v = fmaf(B3[e / 3], Qq[e % 3], v);       // + g4[e]
    v = fmaf(a3[e / 3], B1[e % 3], v);       // + a3 (x) g1
    v = fmaf(a2[e / 9], B2[e % 9], v);       // + a2 (x) g2
    v = fmaf(a1[e / 27], B3[e % 27], v);     // + a1 (x) g3
    a4[e] = v;
  }
#pragma unroll
  for (int e = 0; e < 27; e++) {
    float v = a3[e] + B3[e];
    v = fmaf(a2[e / 3], B1[e % 3], v);
    v = fmaf(a1[e / 9], B2[e % 9], v);
    a3[e] = v;
  }
#pragma unroll
  for (int e = 0; e < 9; e++) a2[e] = fmaf(a1[e / 3], B1[e % 3], a2[e] + B2[e]);
  a1[0] += d0; a1[1] += d1; a1[2] += d2;
}

// Chen product: A := A o B, where B is a packed 120-float state in LDS:
// [0:3)=b1, [3:12)=b2, [12:39)=b3, [39:120)=b4. A covers earlier segments.
__device__ __forceinline__ void chen_combine(float a1[3], float a2[9], float a3[27], float a4[81],
                                             const float* __restrict__ Bs) {
  float B1[3], B2[9], B3[27];
#pragma unroll
  for (int i = 0; i < 3; i++) B1[i] = Bs[i];
#pragma unroll
  for (int i = 0; i < 9; i++) B2[i] = Bs[3 + i];
#pragma unroll
  for (int i = 0; i < 27; i++) B3[i] = Bs[12 + i];

#pragma unroll
  for (int e = 0; e < 81; e++) {
    float v = a4[e] + Bs[39 + e];
    v = fmaf(a3[e / 3], B1[e % 3], v);
    v = fmaf(a2[e / 9], B2[e % 9], v);
    v = fmaf(a1[e / 27], B3[e % 27], v);
    a4[e] = v;
  }
#pragma unroll
  for (int e = 0; e < 27; e++) {
    float v = a3[e] + B3[e];
    v = fmaf(a2[e / 3], B1[e % 3], v);
    v = fmaf(a1[e / 9], B2[e % 9], v);
    a3[e] = v;
  }
#pragma unroll
  for (int e = 0; e < 9; e++) a2[e] = fmaf(a1[e / 3], B1[e % 3], a2[e] + B2[e]);
#pragma unroll
  for (int i = 0; i < 3; i++) a1[i] += B1[i];
}

__device__ __forceinline__ void store_state(float* dst, const float a1[3], const float a2[9],
                                            const float a3[27], const float a4[81]) {
#pragma unroll
  for (int i = 0; i < 3; i++) dst[i] = a1[i];
#pragma unroll
  for (int i = 0; i < 9; i++) dst[3 + i] = a2[i];
#pragma unroll
  for (int i = 0; i < 27; i++) dst[12 + i] = a3[i];
#pragma unroll
  for (int i = 0; i < 81; i++) dst[39 + i] = a4[i];
}

// ---------------------------------------------------------------------------
// Kernel 1: one block (64 lanes) per path. Lane l absorbs segments
// [5l, 5l+5) sequentially in registers, then a 6-level LDS tree applies the
// (non-commutative) Chen product in segment order. Lane 0's state = signature.
// ---------------------------------------------------------------------------
__global__ __launch_bounds__(64) void sig_kernel(const float* __restrict__ inp,
                                                 float* __restrict__ sig) {
  const int p = blockIdx.x;          // path id = b*34 + v*2 + m
  const int b = p / VM;
  const int vm = p - b * VM;
  const int l = threadIdx.x;

  __shared__ float st[64][121];      // pad 121 (odd*?) -> stride 121: conflict-free-ish

  float a1[3], a2[9], a3[27], a4[81];
#pragma unroll
  for (int i = 0; i < 3; i++) a1[i] = 0.f;
#pragma unroll
  for (int i = 0; i < 9; i++) a2[i] = 0.f;
#pragma unroll
  for (int i = 0; i < 27; i++) a3[i] = 0.f;
#pragma unroll
  for (int i = 0; i < 81; i++) a4[i] = 0.f;

  const int t0 = l * CHUNK;
  int nseg = N_SEG - t0;
  nseg = nseg < 0 ? 0 : (nseg > CHUNK ? CHUNK : nseg);

  // inp[b][c][t][vm] flat: ((b*3 + c)*300 + t)*34 + vm
  const float* bp = inp + (size_t)b * 3 * T_PTS * VM + vm;

  if (nseg > 0) {
    float x0 = bp[(0 * T_PTS + t0) * VM];
    float x1 = bp[(1 * T_PTS + t0) * VM];
    float x2 = bp[(2 * T_PTS + t0) * VM];
    float y0 = bp[(0 * T_PTS + t0 + 1) * VM];
    float y1 = bp[(1 * T_PTS + t0 + 1) * VM];
    float y2 = bp[(2 * T_PTS + t0 + 1) * VM];
    for (int s = 0; s < nseg; s++) {
      float z0 = 0.f, z1 = 0.f, z2 = 0.f;
      if (s + 1 < nseg) {            // software prefetch of next point
        const int t = t0 + s + 2;
        z0 = bp[t * VM];
        z1 = bp[(T_PTS + t) * VM];
        z2 = bp[(2 * T_PTS + t) * VM];
      }
      sig_append(a1, a2, a3, a4, y0 - x0, y1 - x1, y2 - x2);
      x0 = y0; x1 = y1; x2 = y2;
      y0 = z0; y1 = z1; y2 = z2;
    }
  }
  // zero-state lanes (l >= 60 tail) are the identity for the Chen product.

  store_state(&st[l][0], a1, a2, a3, a4);
  __syncthreads();

#pragma unroll
  for (int off = 1; off < 64; off <<= 1) {
    if ((l & (2 * off - 1)) == 0) {
      chen_combine(a1, a2, a3, a4, &st[l + off][0]);   // A=earlier, B=later
      store_state(&st[l][0], a1, a2, a3, a4);
    }
    __syncthreads();
  }

  // st[0] now holds the full signature; coalesced write-out.
  const float* src = &st[0][0];
  for (int e = l; e < SIGC; e += 64) sig[(size_t)p * SIGC + e] = src[e];
}

// ---------------------------------------------------------------------------
// Kernel 2a: h[b][j] = b1[j]  (GEMM1 accumulates on top with atomics)
// ---------------------------------------------------------------------------
__global__ __launch_bounds__(256) void hinit_kernel(const float* __restrict__ b1,
                                                    float* __restrict__ h) {
  const int g = blockIdx.x * 256 + threadIdx.x;
  if (g < B_SZ * H1) h[g] = b1[g & (H1 - 1)];
}

// ---------------------------------------------------------------------------
// Kernel 2b: h += S @ W1^T.  S:(64,4080) row-major, W1:(512,4080) row-major.
// Grid: (32 j-tiles of 16) x (8 K-splits of 510). LDS-staged, fp32 FMA,
// atomicAdd epilogue (8 adds per element, order-independent).
// ---------------------------------------------------------------------------
__global__ __launch_bounds__(256) void gemm1_kernel(const float* __restrict__ S,
                                                    const float* __restrict__ W1,
                                                    float* __restrict__ h) {
  const int jt = blockIdx.x;   // 0..31
  const int ks = blockIdx.y;   // 0..7
  const int tid = threadIdx.x;
  __shared__ float Ss[64][103];
  __shared__ float Ws[16][103];
  const int k0 = ks * 510;
  const int r = tid >> 2;      // output row (batch)
  const int cq = tid & 3;      // which 4-col group within 16-wide tile
  float acc0 = 0.f, acc1 = 0.f, acc2 = 0.f, acc3 = 0.f;

  for (int kc = 0; kc < 5; kc++) {
    const int kb = k0 + kc * 102;
    __syncthreads();
    for (int idx = tid; idx < 64 * 102; idx += 256) {
      const int rr = idx / 102, kk = idx - rr * 102;
      Ss[rr][kk] = S[rr * FAN1 + kb + kk];
    }
    for (int idx = tid; idx < 16 * 102; idx += 256) {
      const int jj = idx / 102, kk = idx - jj * 102;
      Ws[jj][kk] = W1[(jt * 16 + jj) * FAN1 + kb + kk];
    }
    __syncthreads();
#pragma unroll 6
    for (int k = 0; k < 102; k++) {
      const float a = Ss[r][k];
      acc0 = fmaf(a, Ws[cq * 4 + 0][k], acc0);
      acc1 = fmaf(a, Ws[cq * 4 + 1][k], acc1);
      acc2 = fmaf(a, Ws[cq * 4 + 2][k], acc2);
      acc3 = fmaf(a, Ws[cq * 4 + 3][k], acc3);
    }
  }
  float* hp = h + r * H1 + jt * 16 + cq * 4;
  atomicAdd(hp + 0, acc0);
  atomicAdd(hp + 1, acc1);
  atomicAdd(hp + 2, acc2);
  atomicAdd(hp + 3, acc3);
}

// ---------------------------------------------------------------------------
// Kernel 3: out[b][j] = h[b] . W2[j] + b2[j].  One wave per (b, j).
// ---------------------------------------------------------------------------
__global__ __launch_bounds__(256) void gemm2_kernel(const float* __restrict__ h,
                                                    const float* __restrict__ W2,
                                                    const float* __restrict__ b2,
                                                    float* __restrict__ out) {
  const int b = blockIdx.x;              // 0..63
  const int jg = blockIdx.y;             // 0..38
  const int wave = threadIdx.x >> 6;     // 0..3
  const int lane = threadIdx.x & 63;
  const int j = jg * 4 + wave;
  if (j >= NOUT) return;
  const float* hb = h + b * H1;
  const float* w = W2 + j * H1;
  float acc = 0.f;
#pragma unroll
  for (int i = 0; i < 8; i++) {
    const int k = lane + i * 64;
    acc = fmaf(hb[k], w[k], acc);
  }
#pragma unroll
  for (int off = 32; off > 0; off >>= 1) acc += __shfl_down(acc, off, 64);
  if (lane == 0) out[b * NOUT + j] = acc + b2[j];
}

// ---------------------------------------------------------------------------
extern "C" void kernel_launch(void* const* d_in, const int* in_sizes, int n_in,
                              void* d_out, int out_size, void* d_ws, size_t ws_size,
                              hipStream_t stream) {
  const float* inp = (const float*)d_in[0];  // (64,3,300,17,2)
  const float* W1  = (const float*)d_in[1];  // (512,4080)
  const float* b1  = (const float*)d_in[2];  // (512,)
  const float* W2  = (const float*)d_in[3];  // (155,512)
  const float* b2  = (const float*)d_in[4];  // (155,)
  float* out = (float*)d_out;                // (64,155)

  float* sig = (float*)d_ws;                                   // 2176*120 floats
  float* h   = (float*)((char*)d_ws + (size_t)NPATH * SIGC * 4); // 64*512 floats

  hinit_kernel<<<(B_SZ * H1 + 255) / 256, 256, 0, stream>>>(b1, h);
  sig_kernel<<<NPATH, 64, 0, stream>>>(inp, sig);
  gemm1_kernel<<<dim3(32, 8), 256, 0, stream>>>(sig, W1, h);
  gemm2_kernel<<<dim3(64, 39), 256, 0, stream>>>(h, W2, b2, out);
}